// Round 7
// baseline (697.836 us; speedup 1.0000x reference)
//
#include <hip/hip_runtime.h>

typedef __attribute__((ext_vector_type(8))) short v8s;
typedef __attribute__((ext_vector_type(4))) float v4f;

#define NB 16
#define TMAX 64
#define B_TOT 8192
#define GP 21      // gbuf padded stride (floats) — conflict-free 16-lane writes

// ws ushort offsets (bf16 fragment regions) — layout identical to round 3/5
#define BL0_U 0        // [n16][kst2][s2][lane64][e8] : 32768 ushorts (Whh0)
#define BL1_U 32768    // [n16][kst4][s2][lane64][e8] : 65536 ushorts (Wih1|Whh1)
#define BFC_U 98304    // [kst2][s2][lane64][e8]      : 2048 ushorts  (Wfc, 13 zero cols)
#define NUSH  100352
#define B0_F  50176    // bih0+bhh0 : 256
#define B1_F  50432    // bih1+bhh1 : 256
#define BFC3_F 50688   // bfc : 3

__device__ __forceinline__ unsigned short f2bh(float f) {
    unsigned u = __float_as_uint(f);
    return (unsigned short)((u + 0x7fffu + ((u >> 16) & 1u)) >> 16);   // RNE to bf16
}
__device__ __forceinline__ float bh2f(unsigned short h) {
    return __uint_as_float(((unsigned)h) << 16);
}
__device__ __forceinline__ float sigm(float x) {
    return 1.f / (1.f + __expf(-x));
}
__device__ __forceinline__ float tanh_(float x) {
    float e = __expf(-2.f * fabsf(x));
    float r = (1.f - e) / (1.f + e);
    return copysignf(r, x);
}
__device__ __forceinline__ v8s ldfrag(const unsigned short* p) { return *(const v8s*)p; }

#define MFMA(a, b, c) __builtin_amdgcn_mfma_f32_16x16x32_bf16((a), (b), (c), 0, 0, 0)

// ---------------------------------------------------------------------------
// repack: UNCHANGED from round 3/5 (HW-verified correct)
// ---------------------------------------------------------------------------
__global__ void repack(const float* __restrict__ Whh0,
                       const float* __restrict__ bih0, const float* __restrict__ bhh0,
                       const float* __restrict__ Wih1, const float* __restrict__ Whh1,
                       const float* __restrict__ bih1, const float* __restrict__ bhh1,
                       const float* __restrict__ Wfc,  const float* __restrict__ bfc,
                       float* __restrict__ wsf) {
    unsigned idx = blockIdx.x * 256 + threadIdx.x;
    unsigned short* wsu = (unsigned short*)wsf;
    if (idx < NUSH) {
        unsigned u, fid, l, e, s, kst, n, r, k;
        float wv;
        if (idx < BL1_U) {
            u = idx; fid = u >> 9; l = (u >> 3) & 63; e = u & 7;
            s = fid & 1; unsigned t = fid >> 1; kst = t & 1; n = t >> 1;
            r = n * 16 + (l & 15); k = kst * 32 + ((l >> 4) * 8) + e;
            wv = Whh0[r * 64 + k];
        } else if (idx < BFC_U) {
            u = idx - BL1_U; fid = u >> 9; l = (u >> 3) & 63; e = u & 7;
            s = fid & 1; unsigned t = fid >> 1; kst = t & 3; n = t >> 2;
            r = n * 16 + (l & 15); k = kst * 32 + ((l >> 4) * 8) + e;
            wv = (k < 64) ? Wih1[r * 64 + k] : Whh1[r * 64 + (k - 64)];
        } else {
            u = idx - BFC_U; fid = u >> 9; l = (u >> 3) & 63; e = u & 7;
            s = fid & 1; kst = fid >> 1;
            unsigned o = l & 15; k = kst * 32 + ((l >> 4) * 8) + e;
            wv = (o < 3) ? Wfc[o * 64 + k] : 0.f;
        }
        unsigned short hi = f2bh(wv);
        wsu[idx] = s ? f2bh(wv - bh2f(hi)) : hi;
    } else {
        unsigned jj = idx - NUSH;
        if (jj < 256) wsf[B0_F + jj] = bih0[jj] + bhh0[jj];
        else if (jj < 512) wsf[B1_F + (jj - 256)] = bih1[jj - 256] + bhh1[jj - 256];
        else if (jj < 515) wsf[BFC3_F + (jj - 512)] = bfc[jj - 512];
    }
}

// ---------------------------------------------------------------------------
// main kernel: 512 wgs x 512 thr (8 waves), 16 batches/wg.
// 2 wg/CU = 4 waves/SIMD; amdgpu_waves_per_eu(4) pins VGPR budget to 128.
// Wave w owns output col-tiles {2w, 2w+1}. Gates recombined via LDS gbuf.
// ---------------------------------------------------------------------------
__global__ __launch_bounds__(512) __attribute__((amdgpu_waves_per_eu(4)))
void lstm_main(
    const float* __restrict__ x0, const float* __restrict__ h_init,
    const float* __restrict__ c_init, const float* __restrict__ Wih0,
    const float* __restrict__ wsf, const int* __restrict__ nsp,
    float* __restrict__ out)
{
    // h tiles in MFMA A-frag order: [buf][split hi/lo][khalf][512]
    __shared__ __align__(16) unsigned short Th0[2][2][2][512];
    __shared__ __align__(16) unsigned short Th1[2][2][2][512];
    __shared__ float gbuf[256][GP];          // gate pre-activations [col][batch]
    __shared__ __align__(16) float xs[2][NB][4];
    __shared__ __align__(16) float obuf[NB][TMAX * 3];

    const unsigned short* wsu = (const unsigned short*)wsf;
    const int tid = threadIdx.x, l = tid & 63, w = tid >> 6;   // w: 0..7
    const int b0g = blockIdx.x * NB;
    const int n = nsp[0];
    const int n0 = 2 * w;                    // first of this wave's 2 col-tiles
    const int colA = n0 * 16 + (l & 15);     // col of ntile 0 (ntile 1 = +16)
    const int bfirst = (l >> 4) * 4;         // first of this lane's 4 D rows
    // activation-phase item mapping: thread owns (ab, aj0) and (ab, aj0+1)
    const int ab = tid >> 5;                 // batch 0..15
    const int aj0 = (tid & 31) << 1;         // even j

    // ---- persistent weights: layer0 hi (16) + layer1 hi kst0,1 (16) ----
    v8s b0h[2][2], b1hA[2][2];
#pragma unroll
    for (int nt = 0; nt < 2; ++nt) {
#pragma unroll
        for (int k = 0; k < 2; ++k) {
            b0h[nt][k]  = ldfrag(wsu + BL0_U + ((((n0 + nt) * 2 + k) * 2 + 0) << 9) + (l << 3));
            b1hA[nt][k] = ldfrag(wsu + BL1_U + ((((n0 + nt) * 4 + k) * 2 + 0) << 9) + (l << 3));
        }
    }
    float bias0[2], bias1[2], wx[2][3];
#pragma unroll
    for (int nt = 0; nt < 2; ++nt) {
        const int cc = colA + nt * 16;
        bias0[nt] = wsf[B0_F + cc];
        bias1[nt] = wsf[B1_F + cc];
#pragma unroll
        for (int oi = 0; oi < 3; ++oi) wx[nt][oi] = Wih0[cc * 3 + oi];
    }
    const float mybfc = ((l & 15) < 3) ? wsf[BFC3_F + (l & 15)] : 0.f;

    // ---- init state (activation mapping: one (b,j) pair per thread) ----
    float c0[2], c1[2];
    {
        const int bg = b0g + ab;
#pragma unroll
        for (int m = 0; m < 2; ++m) {
            const int jj = aj0 + m;
            c0[m] = c_init[bg * 64 + jj];
            c1[m] = c_init[B_TOT * 64 + bg * 64 + jj];
            float h0v = h_init[bg * 64 + jj];
            float h1v = h_init[B_TOT * 64 + bg * 64 + jj];
            const int jh = jj >> 5, kl = jj & 31;
            const int idx = ((kl >> 3) << 7) + (ab << 3) + (kl & 7);
            unsigned short hh = f2bh(h0v);
            Th0[0][0][jh][idx] = hh;
            Th0[0][1][jh][idx] = f2bh(h0v - bh2f(hh));
            hh = f2bh(h1v);
            Th1[0][0][jh][idx] = hh;
            Th1[0][1][jh][idx] = f2bh(h1v - bh2f(hh));
        }
    }
    if (tid < NB * 3) {
        int b = tid / 3, o = tid % 3;
        xs[0][b][o] = x0[(b0g + b) * 3 + o];
    }
    __syncthreads();

    int cur = 0;
    for (int t = 0; t < n; ++t) {
        const int nxt = cur ^ 1;
        // ================= Phase A: layer-0 matmul =================
        v8s b0l[2][2];                       // streamed lo (L2-resident)
#pragma unroll
        for (int nt = 0; nt < 2; ++nt)
#pragma unroll
            for (int k = 0; k < 2; ++k)
                b0l[nt][k] = ldfrag(wsu + BL0_U + ((((n0 + nt) * 2 + k) * 2 + 1) << 9) + (l << 3));

        {
            v4f acc[2];
#pragma unroll
            for (int nt = 0; nt < 2; ++nt)
                acc[nt] = (v4f){bias0[nt], bias0[nt], bias0[nt], bias0[nt]};
            // exact-fp32 input part (K=3)
#pragma unroll
            for (int r = 0; r < 4; ++r) {
                float4 xv = *(const float4*)&xs[cur][bfirst + r][0];
#pragma unroll
                for (int nt = 0; nt < 2; ++nt)
                    acc[nt][r] += wx[nt][0] * xv.x + wx[nt][1] * xv.y + wx[nt][2] * xv.z;
            }
#pragma unroll
            for (int k = 0; k < 2; ++k) {
                v8s ah = *(const v8s*)&Th0[cur][0][k][l * 8];
                v8s al = *(const v8s*)&Th0[cur][1][k][l * 8];
#pragma unroll
                for (int nt = 0; nt < 2; ++nt) {
                    acc[nt] = MFMA(ah, b0h[nt][k], acc[nt]);
                    acc[nt] = MFMA(al, b0h[nt][k], acc[nt]);
                    acc[nt] = MFMA(ah, b0l[nt][k], acc[nt]);
                }
            }
            // write pre-activations (b32 stores: stride GP=21 → conflict-free)
#pragma unroll
            for (int nt = 0; nt < 2; ++nt) {
                const int cc = colA + nt * 16;
#pragma unroll
                for (int r = 0; r < 4; ++r) gbuf[cc][bfirst + r] = acc[nt][r];
            }
        }
        __syncthreads();                     // B1: gates-L0 visible

        // ======== Phase B: layer-0 activations (+ preload C kst0/1 lo) ========
        v8s l01[2][2];
#pragma unroll
        for (int nt = 0; nt < 2; ++nt)
#pragma unroll
            for (int k = 0; k < 2; ++k)
                l01[nt][k] = ldfrag(wsu + BL1_U + ((((n0 + nt) * 4 + k) * 2 + 1) << 9) + (l << 3));

#pragma unroll
        for (int m = 0; m < 2; ++m) {
            const int jj = aj0 + m;
            float ig = sigm(gbuf[jj][ab]);
            float fg = sigm(gbuf[64 + jj][ab]);
            float gg = tanh_(gbuf[128 + jj][ab]);
            float og = sigm(gbuf[192 + jj][ab]);
            float cn = fg * c0[m] + ig * gg;
            c0[m] = cn;
            float h = og * tanh_(cn);
            unsigned short hh = f2bh(h);
            const int jh = jj >> 5, kl = jj & 31;
            const int idx = ((kl >> 3) << 7) + (ab << 3) + (kl & 7);
            Th0[nxt][0][jh][idx] = hh;
            Th0[nxt][1][jh][idx] = f2bh(h - bh2f(hh));
        }
        __syncthreads();                     // B2: h0_new frags visible

        // ================= Phase C: layer-1 matmul =================
        {
            v4f acc[2];
#pragma unroll
            for (int nt = 0; nt < 2; ++nt)
                acc[nt] = (v4f){bias1[nt], bias1[nt], bias1[nt], bias1[nt]};

            v8s h2[2], l2[2];                // stream kst2 (hi+lo)
#pragma unroll
            for (int nt = 0; nt < 2; ++nt) {
                h2[nt] = ldfrag(wsu + BL1_U + ((((n0 + nt) * 4 + 2) * 2 + 0) << 9) + (l << 3));
                l2[nt] = ldfrag(wsu + BL1_U + ((((n0 + nt) * 4 + 2) * 2 + 1) << 9) + (l << 3));
            }
            {   // kst0: A = h0_new khalf0
                v8s ah = *(const v8s*)&Th0[nxt][0][0][l * 8];
                v8s al = *(const v8s*)&Th0[nxt][1][0][l * 8];
#pragma unroll
                for (int nt = 0; nt < 2; ++nt) {
                    acc[nt] = MFMA(ah, b1hA[nt][0], acc[nt]);
                    acc[nt] = MFMA(al, b1hA[nt][0], acc[nt]);
                    acc[nt] = MFMA(ah, l01[nt][0], acc[nt]);
                }
            }
            v8s h3[2], l3[2];                // stream kst3 (hi+lo)
#pragma unroll
            for (int nt = 0; nt < 2; ++nt) {
                h3[nt] = ldfrag(wsu + BL1_U + ((((n0 + nt) * 4 + 3) * 2 + 0) << 9) + (l << 3));
                l3[nt] = ldfrag(wsu + BL1_U + ((((n0 + nt) * 4 + 3) * 2 + 1) << 9) + (l << 3));
            }
            {   // kst1: A = h0_new khalf1
                v8s ah = *(const v8s*)&Th0[nxt][0][1][l * 8];
                v8s al = *(const v8s*)&Th0[nxt][1][1][l * 8];
#pragma unroll
                for (int nt = 0; nt < 2; ++nt) {
                    acc[nt] = MFMA(ah, b1hA[nt][1], acc[nt]);
                    acc[nt] = MFMA(al, b1hA[nt][1], acc[nt]);
                    acc[nt] = MFMA(ah, l01[nt][1], acc[nt]);
                }
            }
            {   // kst2: A = h1_old khalf0
                v8s ah = *(const v8s*)&Th1[cur][0][0][l * 8];
                v8s al = *(const v8s*)&Th1[cur][1][0][l * 8];
#pragma unroll
                for (int nt = 0; nt < 2; ++nt) {
                    acc[nt] = MFMA(ah, h2[nt], acc[nt]);
                    acc[nt] = MFMA(al, h2[nt], acc[nt]);
                    acc[nt] = MFMA(ah, l2[nt], acc[nt]);
                }
            }
            {   // kst3: A = h1_old khalf1
                v8s ah = *(const v8s*)&Th1[cur][0][1][l * 8];
                v8s al = *(const v8s*)&Th1[cur][1][1][l * 8];
#pragma unroll
                for (int nt = 0; nt < 2; ++nt) {
                    acc[nt] = MFMA(ah, h3[nt], acc[nt]);
                    acc[nt] = MFMA(al, h3[nt], acc[nt]);
                    acc[nt] = MFMA(ah, l3[nt], acc[nt]);
                }
            }
#pragma unroll
            for (int nt = 0; nt < 2; ++nt) {
                const int cc = colA + nt * 16;
#pragma unroll
                for (int r = 0; r < 4; ++r) gbuf[cc][bfirst + r] = acc[nt][r];
            }
        }
        __syncthreads();                     // B3: gates-L1 visible

        // ======== Phase D: layer-1 activations (+ wave0 preloads FC frags) ========
        v8s bfh[2], bfl[2];
        if (w == 0) {
#pragma unroll
            for (int k = 0; k < 2; ++k) {
                bfh[k] = ldfrag(wsu + BFC_U + (((k) * 2 + 0) << 9) + (l << 3));
                bfl[k] = ldfrag(wsu + BFC_U + (((k) * 2 + 1) << 9) + (l << 3));
            }
        }
#pragma unroll
        for (int m = 0; m < 2; ++m) {
            const int jj = aj0 + m;
            float ig = sigm(gbuf[jj][ab]);
            float fg = sigm(gbuf[64 + jj][ab]);
            float gg = tanh_(gbuf[128 + jj][ab]);
            float og = sigm(gbuf[192 + jj][ab]);
            float cn = fg * c1[m] + ig * gg;
            c1[m] = cn;
            float h = og * tanh_(cn);
            unsigned short hh = f2bh(h);
            const int jh = jj >> 5, kl = jj & 31;
            const int idx = ((kl >> 3) << 7) + (ab << 3) + (kl & 7);
            Th1[nxt][0][jh][idx] = hh;
            Th1[nxt][1][jh][idx] = f2bh(h - bh2f(hh));
        }
        __syncthreads();                     // B4: h1_new frags visible

        // ================= Phase E: FC head (wave 0) =================
        if (w == 0) {
            v4f af = (v4f){mybfc, mybfc, mybfc, mybfc};
#pragma unroll
            for (int k = 0; k < 2; ++k) {
                v8s ah = *(const v8s*)&Th1[nxt][0][k][l * 8];
                v8s al = *(const v8s*)&Th1[nxt][1][k][l * 8];
                af = MFMA(ah, bfh[k], af);
                af = MFMA(al, bfh[k], af);
                af = MFMA(ah, bfl[k], af);
            }
            if ((l & 15) < 3) {
                const int o = l & 15;
#pragma unroll
                for (int r = 0; r < 4; ++r) {
                    const int b = bfirst + r;
                    float v = af[r];
                    obuf[b][t * 3 + o] = v;
                    xs[nxt][b][o] = v;       // feedback input for next step
                }
            }
        }
        __syncthreads();                     // B5: x_next + buffers settled
        cur = nxt;
    }

    // coalesced output store
    const int tot = NB * n * 3;
    for (int i = tid; i < tot; i += 512) {
        int b = i / (n * 3), r2 = i % (n * 3);
        out[(b0g + b) * (n * 3) + r2] = obuf[b][r2];
    }
}

extern "C" void kernel_launch(void* const* d_in, const int* in_sizes, int n_in,
                              void* d_out, int out_size, void* d_ws, size_t ws_size,
                              hipStream_t stream) {
    const float* x    = (const float*)d_in[0];
    const float* hid  = (const float*)d_in[1];
    const float* cel  = (const float*)d_in[2];
    const float* Wih0 = (const float*)d_in[3];
    const float* Whh0 = (const float*)d_in[4];
    const float* bih0 = (const float*)d_in[5];
    const float* bhh0 = (const float*)d_in[6];
    const float* Wih1 = (const float*)d_in[7];
    const float* Whh1 = (const float*)d_in[8];
    const float* bih1 = (const float*)d_in[9];
    const float* bhh1 = (const float*)d_in[10];
    const float* Wfc  = (const float*)d_in[11];
    const float* bfc  = (const float*)d_in[12];
    const int*   nst  = (const int*)d_in[13];
    float* ws  = (float*)d_ws;
    float* outp = (float*)d_out;

    const int repack_threads = NUSH + 515;
    repack<<<(repack_threads + 255) / 256, 256, 0, stream>>>(
        Whh0, bih0, bhh0, Wih1, Whh1, bih1, bhh1, Wfc, bfc, ws);
    lstm_main<<<B_TOT / NB, 512, 0, stream>>>(x, hid, cel, Wih0, ws, nst, outp);
}

// Round 8
// 449.438 us; speedup vs baseline: 1.5527x; 1.5527x over previous
//
#include <hip/hip_runtime.h>

typedef __attribute__((ext_vector_type(8))) short v8s;
typedef __attribute__((ext_vector_type(4))) float v4f;

#define MB 32          // batches per workgroup (2 MFMA row-tiles)
#define TMAX 64
#define B_TOT 8192
#define GP 33          // gbuf padded stride (batch dim) — conflict-free

// ws ushort offsets (bf16 fragment regions) — layout identical to round 3/5/7
#define BL0_U 0        // [n16][kst2][s2][lane64][e8] : 32768 ushorts (Whh0)
#define BL1_U 32768    // [n16][kst4][s2][lane64][e8] : 65536 ushorts (Wih1|Whh1)
#define BFC_U 98304    // [kst2][s2][lane64][e8]      : 2048 ushorts  (Wfc, 13 zero cols)
#define NUSH  100352
#define B0_F  50176    // bih0+bhh0 : 256
#define B1_F  50432    // bih1+bhh1 : 256
#define BFC3_F 50688   // bfc : 3

__device__ __forceinline__ unsigned short f2bh(float f) {
    unsigned u = __float_as_uint(f);
    return (unsigned short)((u + 0x7fffu + ((u >> 16) & 1u)) >> 16);   // RNE to bf16
}
__device__ __forceinline__ float bh2f(unsigned short h) {
    return __uint_as_float(((unsigned)h) << 16);
}
__device__ __forceinline__ float sigm(float x) {
    return 1.f / (1.f + __expf(-x));
}
__device__ __forceinline__ float tanh_(float x) {
    float e = __expf(-2.f * fabsf(x));
    float r = (1.f - e) / (1.f + e);
    return copysignf(r, x);
}
__device__ __forceinline__ v8s ldfrag(const unsigned short* p) { return *(const v8s*)p; }

#define MFMA(a, b, c) __builtin_amdgcn_mfma_f32_16x16x32_bf16((a), (b), (c), 0, 0, 0)

// ---------------------------------------------------------------------------
// repack: UNCHANGED (HW-verified correct in rounds 3/5/7)
// ---------------------------------------------------------------------------
__global__ void repack(const float* __restrict__ Whh0,
                       const float* __restrict__ bih0, const float* __restrict__ bhh0,
                       const float* __restrict__ Wih1, const float* __restrict__ Whh1,
                       const float* __restrict__ bih1, const float* __restrict__ bhh1,
                       const float* __restrict__ Wfc,  const float* __restrict__ bfc,
                       float* __restrict__ wsf) {
    unsigned idx = blockIdx.x * 256 + threadIdx.x;
    unsigned short* wsu = (unsigned short*)wsf;
    if (idx < NUSH) {
        unsigned u, fid, l, e, s, kst, n, r, k;
        float wv;
        if (idx < BL1_U) {
            u = idx; fid = u >> 9; l = (u >> 3) & 63; e = u & 7;
            s = fid & 1; unsigned t = fid >> 1; kst = t & 1; n = t >> 1;
            r = n * 16 + (l & 15); k = kst * 32 + ((l >> 4) * 8) + e;
            wv = Whh0[r * 64 + k];
        } else if (idx < BFC_U) {
            u = idx - BL1_U; fid = u >> 9; l = (u >> 3) & 63; e = u & 7;
            s = fid & 1; unsigned t = fid >> 1; kst = t & 3; n = t >> 2;
            r = n * 16 + (l & 15); k = kst * 32 + ((l >> 4) * 8) + e;
            wv = (k < 64) ? Wih1[r * 64 + k] : Whh1[r * 64 + (k - 64)];
        } else {
            u = idx - BFC_U; fid = u >> 9; l = (u >> 3) & 63; e = u & 7;
            s = fid & 1; kst = fid >> 1;
            unsigned o = l & 15; k = kst * 32 + ((l >> 4) * 8) + e;
            wv = (o < 3) ? Wfc[o * 64 + k] : 0.f;
        }
        unsigned short hi = f2bh(wv);
        wsu[idx] = s ? f2bh(wv - bh2f(hi)) : hi;
    } else {
        unsigned jj = idx - NUSH;
        if (jj < 256) wsf[B0_F + jj] = bih0[jj] + bhh0[jj];
        else if (jj < 512) wsf[B1_F + (jj - 256)] = bih1[jj - 256] + bhh1[jj - 256];
        else if (jj < 515) wsf[BFC3_F + (jj - 512)] = bfc[jj - 512];
    }
}

// ---------------------------------------------------------------------------
// main kernel: 256 wgs x 512 thr (8 waves), 32 batches/wg → exactly 1 wg/CU
// (LDS 90KB pins it). NO persistent weight registers: every fragment is
// streamed from L2 per use, so per-thread demand (~95) fits any VGPR grant
// the allocator makes — spill-proof by construction.
// Wave w owns col-tiles {2w,2w+1} x row-tiles {0,1}.
// ---------------------------------------------------------------------------
__global__ __launch_bounds__(512)
void lstm_main(
    const float* __restrict__ x0, const float* __restrict__ h_init,
    const float* __restrict__ c_init, const float* __restrict__ Wih0,
    const float* __restrict__ wsf, const int* __restrict__ nsp,
    float* __restrict__ out)
{
    // h tiles in MFMA A-frag order: [buf][split][khalf][rowtile][512]
    __shared__ __align__(16) unsigned short Th0[2][2][2][2][512];   // 16 KB
    __shared__ __align__(16) unsigned short Th1[2][2][2][2][512];   // 16 KB
    __shared__ float gbuf[256][GP];                                  // 33 KB
    __shared__ __align__(16) float xs[2][MB][4];                     // 1 KB
    __shared__ __align__(16) float obuf[MB][TMAX * 3];               // 24 KB

    const unsigned short* wsu = (const unsigned short*)wsf;
    const int tid = threadIdx.x, l = tid & 63, w = tid >> 6;   // w: 0..7
    const int b0g = blockIdx.x * MB;
    const int n = nsp[0];
    const int n0 = 2 * w;                    // first of this wave's 2 col-tiles
    const int colA = n0 * 16 + (l & 15);     // col of ntile 0 (ntile 1 = +16)
    const int bfirst = (l >> 4) * 4;         // first D row within a 16-row tile
    // activation mapping: thread owns batch ab, hidden units ajb..ajb+3
    const int ab = tid & 31;                 // batch 0..31
    const int ajb = (tid >> 5) * 4;          // j base (0,4,...,60)

    float bias0[2], bias1[2], wx[2][3];
#pragma unroll
    for (int nt = 0; nt < 2; ++nt) {
        const int cc = colA + nt * 16;
        bias0[nt] = wsf[B0_F + cc];
        bias1[nt] = wsf[B1_F + cc];
#pragma unroll
        for (int oi = 0; oi < 3; ++oi) wx[nt][oi] = Wih0[cc * 3 + oi];
    }
    const float mybfc = ((l & 15) < 3) ? wsf[BFC3_F + (l & 15)] : 0.f;

    // ---- init state (activation mapping) ----
    float c0[4], c1[4];
    {
        const int bg = b0g + ab;
        const int rt = ab >> 4;
#pragma unroll
        for (int m = 0; m < 4; ++m) {
            const int jj = ajb + m;
            c0[m] = c_init[bg * 64 + jj];
            c1[m] = c_init[B_TOT * 64 + bg * 64 + jj];
            float h0v = h_init[bg * 64 + jj];
            float h1v = h_init[B_TOT * 64 + bg * 64 + jj];
            const int kh = jj >> 5, kl = jj & 31;
            const int idx = ((kl >> 3) << 7) + ((ab & 15) << 3) + (kl & 7);
            unsigned short hh = f2bh(h0v);
            Th0[0][0][kh][rt][idx] = hh;
            Th0[0][1][kh][rt][idx] = f2bh(h0v - bh2f(hh));
            hh = f2bh(h1v);
            Th1[0][0][kh][rt][idx] = hh;
            Th1[0][1][kh][rt][idx] = f2bh(h1v - bh2f(hh));
        }
    }
    if (tid < MB * 3) {
        int b = tid / 3, o = tid % 3;
        xs[0][b][o] = x0[(b0g + b) * 3 + o];
    }
    __syncthreads();

    int cur = 0;
    for (int t = 0; t < n; ++t) {
        const int nxt = cur ^ 1;
        // ================= Phase A: layer-0 matmul =================
        {
            v4f acc[2][2];                   // [nt][rt]
#pragma unroll
            for (int nt = 0; nt < 2; ++nt)
#pragma unroll
                for (int rt = 0; rt < 2; ++rt)
                    acc[nt][rt] = (v4f){bias0[nt], bias0[nt], bias0[nt], bias0[nt]};
            // exact-fp32 input part (K=3)
#pragma unroll
            for (int rt = 0; rt < 2; ++rt)
#pragma unroll
                for (int r = 0; r < 4; ++r) {
                    float4 xv = *(const float4*)&xs[cur][rt * 16 + bfirst + r][0];
#pragma unroll
                    for (int nt = 0; nt < 2; ++nt)
                        acc[nt][rt][r] += wx[nt][0] * xv.x + wx[nt][1] * xv.y + wx[nt][2] * xv.z;
                }
            // recurrent part: stream B hi+lo from L2 per kstep
#pragma unroll
            for (int k = 0; k < 2; ++k) {
                v8s bh[2], bl[2];
#pragma unroll
                for (int nt = 0; nt < 2; ++nt) {
                    bh[nt] = ldfrag(wsu + BL0_U + ((((n0 + nt) * 2 + k) * 2 + 0) << 9) + (l << 3));
                    bl[nt] = ldfrag(wsu + BL0_U + ((((n0 + nt) * 2 + k) * 2 + 1) << 9) + (l << 3));
                }
#pragma unroll
                for (int rt = 0; rt < 2; ++rt) {
                    v8s ah = *(const v8s*)&Th0[cur][0][k][rt][l * 8];
                    v8s al = *(const v8s*)&Th0[cur][1][k][rt][l * 8];
#pragma unroll
                    for (int nt = 0; nt < 2; ++nt) {
                        acc[nt][rt] = MFMA(ah, bh[nt], acc[nt][rt]);
                        acc[nt][rt] = MFMA(al, bh[nt], acc[nt][rt]);
                        acc[nt][rt] = MFMA(ah, bl[nt], acc[nt][rt]);
                    }
                }
            }
#pragma unroll
            for (int nt = 0; nt < 2; ++nt)
#pragma unroll
                for (int rt = 0; rt < 2; ++rt)
#pragma unroll
                    for (int r = 0; r < 4; ++r)
                        gbuf[colA + nt * 16][rt * 16 + bfirst + r] = acc[nt][rt][r];
        }
        __syncthreads();                     // B1: gates-L0 visible

        // ================= Phase B: layer-0 activations =================
        {
            const int rt = ab >> 4;
#pragma unroll
            for (int m = 0; m < 4; ++m) {
                const int jj = ajb + m;
                float ig = sigm(gbuf[jj][ab]);
                float fg = sigm(gbuf[64 + jj][ab]);
                float gg = tanh_(gbuf[128 + jj][ab]);
                float og = sigm(gbuf[192 + jj][ab]);
                float cn = fg * c0[m] + ig * gg;
                c0[m] = cn;
                float h = og * tanh_(cn);
                unsigned short hh = f2bh(h);
                const int kh = jj >> 5, kl = jj & 31;
                const int idx = ((kl >> 3) << 7) + ((ab & 15) << 3) + (kl & 7);
                Th0[nxt][0][kh][rt][idx] = hh;
                Th0[nxt][1][kh][rt][idx] = f2bh(h - bh2f(hh));
            }
        }
        __syncthreads();                     // B2: h0_new frags visible

        // ================= Phase C: layer-1 matmul =================
        {
            v4f acc[2][2];
#pragma unroll
            for (int nt = 0; nt < 2; ++nt)
#pragma unroll
                for (int rt = 0; rt < 2; ++rt)
                    acc[nt][rt] = (v4f){bias1[nt], bias1[nt], bias1[nt], bias1[nt]};
#pragma unroll
            for (int k = 0; k < 4; ++k) {
                v8s bh[2], bl[2];
#pragma unroll
                for (int nt = 0; nt < 2; ++nt) {
                    bh[nt] = ldfrag(wsu + BL1_U + ((((n0 + nt) * 4 + k) * 2 + 0) << 9) + (l << 3));
                    bl[nt] = ldfrag(wsu + BL1_U + ((((n0 + nt) * 4 + k) * 2 + 1) << 9) + (l << 3));
                }
#pragma unroll
                for (int rt = 0; rt < 2; ++rt) {
                    v8s ah, al;
                    if (k < 2) { ah = *(const v8s*)&Th0[nxt][0][k][rt][l * 8];
                                 al = *(const v8s*)&Th0[nxt][1][k][rt][l * 8]; }
                    else       { ah = *(const v8s*)&Th1[cur][0][k - 2][rt][l * 8];
                                 al = *(const v8s*)&Th1[cur][1][k - 2][rt][l * 8]; }
#pragma unroll
                    for (int nt = 0; nt < 2; ++nt) {
                        acc[nt][rt] = MFMA(ah, bh[nt], acc[nt][rt]);
                        acc[nt][rt] = MFMA(al, bh[nt], acc[nt][rt]);
                        acc[nt][rt] = MFMA(ah, bl[nt], acc[nt][rt]);
                    }
                }
            }
#pragma unroll
            for (int nt = 0; nt < 2; ++nt)
#pragma unroll
                for (int rt = 0; rt < 2; ++rt)
#pragma unroll
                    for (int r = 0; r < 4; ++r)
                        gbuf[colA + nt * 16][rt * 16 + bfirst + r] = acc[nt][rt][r];
        }
        __syncthreads();                     // B3: gates-L1 visible

        // ================= Phase D: layer-1 activations =================
        {
            const int rt = ab >> 4;
#pragma unroll
            for (int m = 0; m < 4; ++m) {
                const int jj = ajb + m;
                float ig = sigm(gbuf[jj][ab]);
                float fg = sigm(gbuf[64 + jj][ab]);
                float gg = tanh_(gbuf[128 + jj][ab]);
                float og = sigm(gbuf[192 + jj][ab]);
                float cn = fg * c1[m] + ig * gg;
                c1[m] = cn;
                float h = og * tanh_(cn);
                unsigned short hh = f2bh(h);
                const int kh = jj >> 5, kl = jj & 31;
                const int idx = ((kl >> 3) << 7) + ((ab & 15) << 3) + (kl & 7);
                Th1[nxt][0][kh][rt][idx] = hh;
                Th1[nxt][1][kh][rt][idx] = f2bh(h - bh2f(hh));
            }
        }
        __syncthreads();                     // B4: h1_new frags visible

        // ================= Phase E: FC head (wave 0) =================
        if (w == 0) {
            v8s bfh[2], bfl[2];
#pragma unroll
            for (int k = 0; k < 2; ++k) {
                bfh[k] = ldfrag(wsu + BFC_U + ((k * 2 + 0) << 9) + (l << 3));
                bfl[k] = ldfrag(wsu + BFC_U + ((k * 2 + 1) << 9) + (l << 3));
            }
#pragma unroll
            for (int rt = 0; rt < 2; ++rt) {
                v4f af = (v4f){mybfc, mybfc, mybfc, mybfc};
#pragma unroll
                for (int k = 0; k < 2; ++k) {
                    v8s ah = *(const v8s*)&Th1[nxt][0][k][rt][l * 8];
                    v8s al = *(const v8s*)&Th1[nxt][1][k][rt][l * 8];
                    af = MFMA(ah, bfh[k], af);
                    af = MFMA(al, bfh[k], af);
                    af = MFMA(ah, bfl[k], af);
                }
                if ((l & 15) < 3) {
                    const int o = l & 15;
#pragma unroll
                    for (int r = 0; r < 4; ++r) {
                        const int b = rt * 16 + bfirst + r;
                        float v = af[r];
                        obuf[b][t * 3 + o] = v;
                        xs[nxt][b][o] = v;   // feedback input for next step
                    }
                }
            }
        }
        __syncthreads();                     // B5: x_next + buffers settled
        cur = nxt;
    }

    // coalesced output store
    const int tot = MB * n * 3;
    for (int i = tid; i < tot; i += 512) {
        int b = i / (n * 3), r2 = i % (n * 3);
        out[(b0g + b) * (n * 3) + r2] = obuf[b][r2];
    }
}

extern "C" void kernel_launch(void* const* d_in, const int* in_sizes, int n_in,
                              void* d_out, int out_size, void* d_ws, size_t ws_size,
                              hipStream_t stream) {
    const float* x    = (const float*)d_in[0];
    const float* hid  = (const float*)d_in[1];
    const float* cel  = (const float*)d_in[2];
    const float* Wih0 = (const float*)d_in[3];
    const float* Whh0 = (const float*)d_in[4];
    const float* bih0 = (const float*)d_in[5];
    const float* bhh0 = (const float*)d_in[6];
    const float* Wih1 = (const float*)d_in[7];
    const float* Whh1 = (const float*)d_in[8];
    const float* bih1 = (const float*)d_in[9];
    const float* bhh1 = (const float*)d_in[10];
    const float* Wfc  = (const float*)d_in[11];
    const float* bfc  = (const float*)d_in[12];
    const int*   nst  = (const int*)d_in[13];
    float* ws  = (float*)d_ws;
    float* outp = (float*)d_out;

    const int repack_threads = NUSH + 515;
    repack<<<(repack_threads + 255) / 256, 256, 0, stream>>>(
        Whh0, bih0, bhh0, Wih1, Whh1, bih1, bhh1, Wfc, bfc, ws);
    lstm_main<<<B_TOT / MB, 512, 0, stream>>>(x, hid, cel, Wih0, ws, nst, outp);
}